// Round 9
// baseline (57.197 us; speedup 1.0000x reference)
//
#include <hip/hip_runtime.h>

#define NT    512                // 8 waves per block
#define NWV   8
#define WIN   8192               // block window (floats)
#define VALID 7168               // valid outputs per block (halo 1024)
#define C     16                 // elements per lane per array

// tb: 8192 floats (32 KB), multi-purposed:
//   transpose buffer (h then x, sequentially), per-wave quarter [wv*1024,+1024)
//   phase-B halo regions (words), consecutive-layer disjoint:
//     R16:[0,1024) R32:[1024,2048) M1:[0,1024) M2:[1024,3072) M4:[3072,7168)
//     M8:[0,8192) with pre-barrier (overlaps M4's read region)
#define R16B 0
#define R32B 1024
#define M1B  0
#define M2B  1024
#define M4B  3072
#define M8B  0

// XOR-swizzle for the transpose pattern: word bits 2..4 ^= bits 5..7
// (lane bits 1..3 of lane*16). Measured 0 conflicts in R7/R8.
__device__ __forceinline__ int tswz(int w) { return w ^ (((w >> 5) & 7) << 2); }

__device__ __forceinline__ float fast_tanh(float y) {
    // tanh(y) = 1 - 2/(exp(2y)+1); exp via exp2. Saturates correctly at +/-inf.
    float e = __builtin_amdgcn_exp2f(y * 2.885390081777927f);
    float r = __builtin_amdgcn_rcpf(e + 1.0f);
    return fmaf(-2.0f, r, 1.0f);
}

// ---------------- Phase A: contiguous layout, D in {1,2,4,8} ----------------
// Lane owns elements [16*(64*wv+lane), +16). Tail j+D>=16 from lane+1 via shfl;
// lane 63 reads next wave's published head. Wave 7 wraps to wave 0 -> garbage
// lands only in the invalid block tail (valid prefix stays >= 7169).
template<int D, int I>
__device__ __forceinline__ void layerA(float (&h)[C], float (&x)[C],
        const float* wh, const float* wx, int lane, int wv,
        float (*hA)[NWV][2][8])
{
    const float wh0 = wh[2*I], wh1 = wh[2*I+1];
    const float wx0 = wx[2*I], wx1 = wx[2*I+1];
    const int nw = (wv + 1) & (NWV - 1);

    if (lane == 0) {
        #pragma unroll
        for (int j = 0; j < D; ++j) { hA[I][wv][0][j] = h[j]; hA[I][wv][1][j] = x[j]; }
    }
    __syncthreads();

    float th[D], tx[D];
    #pragma unroll
    for (int j = 0; j < D; ++j) {
        th[j] = __shfl(h[j], (lane + 1) & 63, 64);
        tx[j] = __shfl(x[j], (lane + 1) & 63, 64);
        if (lane == 63) { th[j] = hA[I][nw][0][j]; tx[j] = hA[I][nw][1][j]; }
    }
    #pragma unroll
    for (int j = 0; j < C; ++j) {           // ascending j: h[j+D]/x[j+D] still old
        float hd = (j + D < C) ? h[j + D] : th[j + D - C];
        float xd = (j + D < C) ? x[j + D] : tx[j + D - C];
        float hn = fmaf(wh0, h[j], wh1 * hd);
        float s  = fmaf(wx0, x[j], hn);
        s        = fmaf(wx1, xd, s);
        h[j] = hn;
        x[j] = fast_tanh(s);
    }
    // region hA[I] never reused -> single barrier per layer is WAR-safe
}

// ------------- Phase B: stride-64 interleave, slot k = element lane+64k -------------
// halo word: BASE + ((wv*2 + arr)*M + s)*64 + lane  (lane-contiguous, conflict-free)

// D = R (16 or 32): j+R -> lane (l+R)&63, slot k (+1 for high lanes).
template<int R, int BASE, int I>
__device__ __forceinline__ void layerBR(float (&hh)[C], float (&xx)[C],
        const float* wh, const float* wx, int lane, int wv, float* tb)
{
    const float wh0 = wh[2*I], wh1 = wh[2*I+1];
    const float wx0 = wx[2*I], wx1 = wx[2*I+1];
    const int nw = (wv + 1) & (NWV - 1);

    tb[BASE + (wv*2+0)*64 + lane] = hh[0];     // publish slot 0 (all lanes)
    tb[BASE + (wv*2+1)*64 + lane] = xx[0];
    __syncthreads();

    float fh[C + 1], fx[C + 1];
    #pragma unroll
    for (int k = 0; k < C; ++k) {
        fh[k] = __shfl(hh[k], (lane + R) & 63, 64);
        fx[k] = __shfl(xx[k], (lane + R) & 63, 64);
    }
    fh[C] = 0.0f; fx[C] = 0.0f;
    if (lane >= 64 - R) {                      // slot-16 = next wave's slot 0
        fh[C] = tb[BASE + (nw*2+0)*64 + (lane - (64 - R))];
        fx[C] = tb[BASE + (nw*2+1)*64 + (lane - (64 - R))];
    }
    const bool lo = lane < 64 - R;
    #pragma unroll
    for (int k = 0; k < C; ++k) {
        float hd = lo ? fh[k] : fh[k + 1];
        float xd = lo ? fx[k] : fx[k + 1];
        float hn = fmaf(wh0, hh[k], wh1 * hd);
        float s  = fmaf(wx0, xx[k], hn);
        s        = fmaf(wx1, xd, s);
        hh[k] = hn;
        xx[k] = fast_tanh(s);
    }
}

// D = 64*M (M in {1,2,4,8}): pure slot shift; only slots >= 16-M cross the wave.
template<int M, int BASE, bool PREBAR, int I>
__device__ __forceinline__ void layerBM(float (&hh)[C], float (&xx)[C],
        const float* wh, const float* wx, int lane, int wv, float* tb)
{
    const float wh0 = wh[2*I], wh1 = wh[2*I+1];
    const float wx0 = wx[2*I], wx1 = wx[2*I+1];
    const int nw = (wv + 1) & (NWV - 1);

    if constexpr (PREBAR) __syncthreads();     // M=8 overwrites prior read regions

    #pragma unroll
    for (int s = 0; s < M; ++s) {              // publish head slots
        tb[BASE + ((wv*2+0)*M + s)*64 + lane] = hh[s];
        tb[BASE + ((wv*2+1)*M + s)*64 + lane] = xx[s];
    }
    __syncthreads();

    float nh[M], nx[M];
    #pragma unroll
    for (int s = 0; s < M; ++s) {              // next wave's head slots
        nh[s] = tb[BASE + ((nw*2+0)*M + s)*64 + lane];
        nx[s] = tb[BASE + ((nw*2+1)*M + s)*64 + lane];
    }
    #pragma unroll
    for (int k = 0; k < C; ++k) {              // ascending k: hh[k+M] still old
        float hd = (k + M < C) ? hh[k + M] : nh[k + M - C];
        float xd = (k + M < C) ? xx[k + M] : nx[k + M - C];
        float hn = fmaf(wh0, hh[k], wh1 * hd);
        float s  = fmaf(wx0, xx[k], hn);
        s        = fmaf(wx1, xd, s);
        hh[k] = hn;
        xx[k] = fast_tanh(s);
    }
}

__global__ __launch_bounds__(NT, 8) void rawstack_w8(
    const float* __restrict__ hin, const float* __restrict__ xin,
    const float* __restrict__ wh,  const float* __restrict__ wx,
    float* __restrict__ out, int T, int Lout)
{
    __shared__ __align__(16) float tb[WIN];    // 32 KB shared transpose/halo buffer
    __shared__ float hA[4][NWV][2][8];         // 2 KB phase-A head halos

    const int lane = threadIdx.x & 63;
    const int wv   = threadIdx.x >> 6;
    const int b    = blockIdx.y;
    const int W    = blockIdx.x * VALID;

    const float* hb = hin + (size_t)b * T;
    const float* xb = xin + (size_t)b * T;

    // ---- load contiguous chunks (clamped; garbage stays in invalid tail) ----
    float h[C], x[C];
    #pragma unroll
    for (int q = 0; q < C / 4; ++q) {
        int e = W + wv * 1024 + lane * C + q * 4;
        e = (e > T - 4) ? (T - 4) : e;
        const float4 hv = *(const float4*)(hb + e);
        const float4 xv = *(const float4*)(xb + e);
        h[q*4+0] = hv.x; h[q*4+1] = hv.y; h[q*4+2] = hv.z; h[q*4+3] = hv.w;
        x[q*4+0] = xv.x; x[q*4+1] = xv.y; x[q*4+2] = xv.z; x[q*4+3] = xv.w;
    }

    // ---- phase A: D = 1,2,4,8 ----
    layerA<1, 0>(h, x, wh, wx, lane, wv, hA);
    layerA<2, 1>(h, x, wh, wx, lane, wv, hA);
    layerA<4, 2>(h, x, wh, wx, lane, wv, hA);
    layerA<8, 3>(h, x, wh, wx, lane, wv, hA);

    // ---- transpose to stride-64 interleave, h then x through the SAME 32 KB ----
    float hh[C], xx[C];
    #pragma unroll
    for (int q = 0; q < C / 4; ++q) {
        const int w = tswz(wv * 1024 + lane * C + q * 4);
        *(float4*)&tb[w] = make_float4(h[q*4+0], h[q*4+1], h[q*4+2], h[q*4+3]);
    }
    __syncthreads();
    #pragma unroll
    for (int k = 0; k < C; ++k) hh[k] = tb[tswz(wv * 1024 + lane + 64 * k)];
    __syncthreads();                           // all h-reads done before x overwrites
    #pragma unroll
    for (int q = 0; q < C / 4; ++q) {
        const int w = tswz(wv * 1024 + lane * C + q * 4);
        *(float4*)&tb[w] = make_float4(x[q*4+0], x[q*4+1], x[q*4+2], x[q*4+3]);
    }
    __syncthreads();
    #pragma unroll
    for (int k = 0; k < C; ++k) xx[k] = tb[tswz(wv * 1024 + lane + 64 * k)];
    __syncthreads();                           // all x-reads done before halo publishes

    // ---- phase B: D = 16,32 (shuffle+select), D = 64..512 (slot shift) ----
    layerBR<16, R16B,        4>(hh, xx, wh, wx, lane, wv, tb);
    layerBR<32, R32B,        5>(hh, xx, wh, wx, lane, wv, tb);
    layerBM< 1, M1B,  false, 6>(hh, xx, wh, wx, lane, wv, tb);   // D=64
    layerBM< 2, M2B,  false, 7>(hh, xx, wh, wx, lane, wv, tb);   // D=128
    layerBM< 4, M4B,  false, 8>(hh, xx, wh, wx, lane, wv, tb);   // D=256
    layerBM< 8, M8B,  true,  9>(hh, xx, wh, wx, lane, wv, tb);   // D=512, full tb

    // ---- store (interleaved layout; waves 0..6 hold the 7168 valid outputs) ----
    if (wv < 7) {
        float* ob = out + (size_t)b * Lout;
        const int base = W + wv * 1024 + lane;
        #pragma unroll
        for (int k = 0; k < C; ++k) {
            const int col = base + 64 * k;
            if (col < Lout) ob[col] = xx[k];
        }
    }
}

extern "C" void kernel_launch(void* const* d_in, const int* in_sizes, int n_in,
                              void* d_out, int out_size, void* d_ws, size_t ws_size,
                              hipStream_t stream) {
    const float* h  = (const float*)d_in[0];
    const float* x  = (const float*)d_in[1];
    const float* wh = (const float*)d_in[2];
    const float* wx = (const float*)d_in[3];
    float* out = (float*)d_out;

    const int B    = 64;
    const int T    = in_sizes[0] / B;   // 131072
    const int Lout = out_size / B;      // 130049

    const int blocksPerRow = (Lout + VALID - 1) / VALID;   // 19

    dim3 grid(blocksPerRow, B);
    rawstack_w8<<<grid, NT, 0, stream>>>(h, x, wh, wx, out, T, Lout);
}

// Round 10
// 51.392 us; speedup vs baseline: 1.1130x; 1.1130x over previous
//
#include <hip/hip_runtime.h>

#define NT    512                // 8 waves per block
#define NWV   8
#define WIN   8192               // block window (floats)
#define VALID 7168               // valid outputs per block (halo 1024)
#define C     16                 // elements per lane per array

// tb: 8192 floats (32 KB), multi-purposed:
//   transpose buffer (h then x, sequentially), per-wave quarter [wv*1024,+1024)
//   phase-B halo regions (words), consecutive-layer disjoint:
//     R16:[0,1024) R32:[1024,2048) M1:[0,1024) M2:[1024,3072) M4:[3072,7168)
//     M8:[0,8192) with pre-barrier (overlaps M4's read region)
#define R16B 0
#define R32B 1024
#define M1B  0
#define M2B  1024
#define M4B  3072
#define M8B  0

// XOR-swizzle for the transpose pattern: word bits 2..4 ^= bits 5..7
// (lane bits 1..3 of lane*16). Measured 0 conflicts in R7/R8.
__device__ __forceinline__ int tswz(int w) { return w ^ (((w >> 5) & 7) << 2); }

__device__ __forceinline__ float fast_tanh(float y) {
    // tanh(y) = 1 - 2/(exp(2y)+1); exp via exp2. Saturates correctly at +/-inf.
    float e = __builtin_amdgcn_exp2f(y * 2.885390081777927f);
    float r = __builtin_amdgcn_rcpf(e + 1.0f);
    return fmaf(-2.0f, r, 1.0f);
}

// ---------------- Phase A: contiguous layout, D in {1,2,4,8} ----------------
// Lane owns elements [16*(64*wv+lane), +16). Tail j+D>=16 from lane+1 via shfl;
// lane 63 reads next wave's published head. Wave 7 wraps to wave 0 -> garbage
// lands only in the invalid block tail (valid prefix stays >= 7169).
template<int D, int I>
__device__ __forceinline__ void layerA(float (&h)[C], float (&x)[C],
        const float* wh, const float* wx, int lane, int wv,
        float (*hA)[NWV][2][8])
{
    const float wh0 = wh[2*I], wh1 = wh[2*I+1];
    const float wx0 = wx[2*I], wx1 = wx[2*I+1];
    const int nw = (wv + 1) & (NWV - 1);

    if (lane == 0) {
        #pragma unroll
        for (int j = 0; j < D; ++j) { hA[I][wv][0][j] = h[j]; hA[I][wv][1][j] = x[j]; }
    }
    __syncthreads();

    float th[D], tx[D];
    #pragma unroll
    for (int j = 0; j < D; ++j) {
        th[j] = __shfl(h[j], (lane + 1) & 63, 64);
        tx[j] = __shfl(x[j], (lane + 1) & 63, 64);
        if (lane == 63) { th[j] = hA[I][nw][0][j]; tx[j] = hA[I][nw][1][j]; }
    }
    #pragma unroll
    for (int j = 0; j < C; ++j) {           // ascending j: h[j+D]/x[j+D] still old
        float hd = (j + D < C) ? h[j + D] : th[j + D - C];
        float xd = (j + D < C) ? x[j + D] : tx[j + D - C];
        float hn = fmaf(wh0, h[j], wh1 * hd);
        float s  = fmaf(wx0, x[j], hn);
        s        = fmaf(wx1, xd, s);
        h[j] = hn;
        x[j] = fast_tanh(s);
    }
    // region hA[I] never reused -> single barrier per layer is WAR-safe
}

// ------------- Phase B: stride-64 interleave, slot k = element lane+64k -------------
// halo word: BASE + ((wv*2 + arr)*M + s)*64 + lane  (lane-contiguous, conflict-free)

// D = R (16 or 32): j+R -> lane (l+R)&63, slot k (+1 for high lanes).
template<int R, int BASE, int I>
__device__ __forceinline__ void layerBR(float (&hh)[C], float (&xx)[C],
        const float* wh, const float* wx, int lane, int wv, float* tb)
{
    const float wh0 = wh[2*I], wh1 = wh[2*I+1];
    const float wx0 = wx[2*I], wx1 = wx[2*I+1];
    const int nw = (wv + 1) & (NWV - 1);

    tb[BASE + (wv*2+0)*64 + lane] = hh[0];     // publish slot 0 (all lanes)
    tb[BASE + (wv*2+1)*64 + lane] = xx[0];
    __syncthreads();

    float fh[C + 1], fx[C + 1];
    #pragma unroll
    for (int k = 0; k < C; ++k) {
        fh[k] = __shfl(hh[k], (lane + R) & 63, 64);
        fx[k] = __shfl(xx[k], (lane + R) & 63, 64);
    }
    fh[C] = 0.0f; fx[C] = 0.0f;
    if (lane >= 64 - R) {                      // slot-16 = next wave's slot 0
        fh[C] = tb[BASE + (nw*2+0)*64 + (lane - (64 - R))];
        fx[C] = tb[BASE + (nw*2+1)*64 + (lane - (64 - R))];
    }
    const bool lo = lane < 64 - R;
    #pragma unroll
    for (int k = 0; k < C; ++k) {
        float hd = lo ? fh[k] : fh[k + 1];
        float xd = lo ? fx[k] : fx[k + 1];
        float hn = fmaf(wh0, hh[k], wh1 * hd);
        float s  = fmaf(wx0, xx[k], hn);
        s        = fmaf(wx1, xd, s);
        hh[k] = hn;
        xx[k] = fast_tanh(s);
    }
}

// D = 64*M (M in {1,2,4,8}): pure slot shift; only slots >= 16-M cross the wave.
template<int M, int BASE, bool PREBAR, int I>
__device__ __forceinline__ void layerBM(float (&hh)[C], float (&xx)[C],
        const float* wh, const float* wx, int lane, int wv, float* tb)
{
    const float wh0 = wh[2*I], wh1 = wh[2*I+1];
    const float wx0 = wx[2*I], wx1 = wx[2*I+1];
    const int nw = (wv + 1) & (NWV - 1);

    if constexpr (PREBAR) __syncthreads();     // M=8 overwrites prior read regions

    #pragma unroll
    for (int s = 0; s < M; ++s) {              // publish head slots
        tb[BASE + ((wv*2+0)*M + s)*64 + lane] = hh[s];
        tb[BASE + ((wv*2+1)*M + s)*64 + lane] = xx[s];
    }
    __syncthreads();

    float nh[M], nx[M];
    #pragma unroll
    for (int s = 0; s < M; ++s) {              // next wave's head slots
        nh[s] = tb[BASE + ((nw*2+0)*M + s)*64 + lane];
        nx[s] = tb[BASE + ((nw*2+1)*M + s)*64 + lane];
    }
    #pragma unroll
    for (int k = 0; k < C; ++k) {              // ascending k: hh[k+M] still old
        float hd = (k + M < C) ? hh[k + M] : nh[k + M - C];
        float xd = (k + M < C) ? xx[k + M] : nx[k + M - C];
        float hn = fmaf(wh0, hh[k], wh1 * hd);
        float s  = fmaf(wx0, xx[k], hn);
        s        = fmaf(wx1, xd, s);
        hh[k] = hn;
        xx[k] = fast_tanh(s);
    }
}

// launch_bounds arg2: empirical VGPR cap = 256/arg2 (R2/R3/R4/R9).
// arg2=4 -> cap 64: natural usage ~40-52 fits, no spills; runtime occupancy
// still reaches 4 blocks x 8 waves = 32 waves/CU since actual VGPR <= 64.
__global__ __launch_bounds__(NT, 4) void rawstack_w8(
    const float* __restrict__ hin, const float* __restrict__ xin,
    const float* __restrict__ wh,  const float* __restrict__ wx,
    float* __restrict__ out, int T, int Lout)
{
    __shared__ __align__(16) float tb[WIN];    // 32 KB shared transpose/halo buffer
    __shared__ float hA[4][NWV][2][8];         // 2 KB phase-A head halos

    const int lane = threadIdx.x & 63;
    const int wv   = threadIdx.x >> 6;
    const int b    = blockIdx.y;
    const int W    = blockIdx.x * VALID;

    const float* hb = hin + (size_t)b * T;
    const float* xb = xin + (size_t)b * T;

    // ---- load contiguous chunks (clamped; garbage stays in invalid tail) ----
    float h[C], x[C];
    #pragma unroll
    for (int q = 0; q < C / 4; ++q) {
        int e = W + wv * 1024 + lane * C + q * 4;
        e = (e > T - 4) ? (T - 4) : e;
        const float4 hv = *(const float4*)(hb + e);
        const float4 xv = *(const float4*)(xb + e);
        h[q*4+0] = hv.x; h[q*4+1] = hv.y; h[q*4+2] = hv.z; h[q*4+3] = hv.w;
        x[q*4+0] = xv.x; x[q*4+1] = xv.y; x[q*4+2] = xv.z; x[q*4+3] = xv.w;
    }

    // ---- phase A: D = 1,2,4,8 ----
    layerA<1, 0>(h, x, wh, wx, lane, wv, hA);
    layerA<2, 1>(h, x, wh, wx, lane, wv, hA);
    layerA<4, 2>(h, x, wh, wx, lane, wv, hA);
    layerA<8, 3>(h, x, wh, wx, lane, wv, hA);

    // ---- transpose to stride-64 interleave, h then x through the SAME 32 KB ----
    float hh[C], xx[C];
    #pragma unroll
    for (int q = 0; q < C / 4; ++q) {
        const int w = tswz(wv * 1024 + lane * C + q * 4);
        *(float4*)&tb[w] = make_float4(h[q*4+0], h[q*4+1], h[q*4+2], h[q*4+3]);
    }
    __syncthreads();
    #pragma unroll
    for (int k = 0; k < C; ++k) hh[k] = tb[tswz(wv * 1024 + lane + 64 * k)];
    __syncthreads();                           // all h-reads done before x overwrites
    #pragma unroll
    for (int q = 0; q < C / 4; ++q) {
        const int w = tswz(wv * 1024 + lane * C + q * 4);
        *(float4*)&tb[w] = make_float4(x[q*4+0], x[q*4+1], x[q*4+2], x[q*4+3]);
    }
    __syncthreads();
    #pragma unroll
    for (int k = 0; k < C; ++k) xx[k] = tb[tswz(wv * 1024 + lane + 64 * k)];
    __syncthreads();                           // all x-reads done before halo publishes

    // ---- phase B: D = 16,32 (shuffle+select), D = 64..512 (slot shift) ----
    layerBR<16, R16B,        4>(hh, xx, wh, wx, lane, wv, tb);
    layerBR<32, R32B,        5>(hh, xx, wh, wx, lane, wv, tb);
    layerBM< 1, M1B,  false, 6>(hh, xx, wh, wx, lane, wv, tb);   // D=64
    layerBM< 2, M2B,  false, 7>(hh, xx, wh, wx, lane, wv, tb);   // D=128
    layerBM< 4, M4B,  false, 8>(hh, xx, wh, wx, lane, wv, tb);   // D=256
    layerBM< 8, M8B,  true,  9>(hh, xx, wh, wx, lane, wv, tb);   // D=512, full tb

    // ---- store (interleaved layout; waves 0..6 hold the 7168 valid outputs) ----
    if (wv < 7) {
        float* ob = out + (size_t)b * Lout;
        const int base = W + wv * 1024 + lane;
        #pragma unroll
        for (int k = 0; k < C; ++k) {
            const int col = base + 64 * k;
            if (col < Lout) ob[col] = xx[k];
        }
    }
}

extern "C" void kernel_launch(void* const* d_in, const int* in_sizes, int n_in,
                              void* d_out, int out_size, void* d_ws, size_t ws_size,
                              hipStream_t stream) {
    const float* h  = (const float*)d_in[0];
    const float* x  = (const float*)d_in[1];
    const float* wh = (const float*)d_in[2];
    const float* wx = (const float*)d_in[3];
    float* out = (float*)d_out;

    const int B    = 64;
    const int T    = in_sizes[0] / B;   // 131072
    const int Lout = out_size / B;      // 130049

    const int blocksPerRow = (Lout + VALID - 1) / VALID;   // 19

    dim3 grid(blocksPerRow, B);
    rawstack_w8<<<grid, NT, 0, stream>>>(h, x, wh, wx, out, T, Lout);
}

// Round 11
// 47.289 us; speedup vs baseline: 1.2095x; 1.0868x over previous
//
#include <hip/hip_runtime.h>

#define NT    512                // 8 waves per block
#define NWV   8
#define WIN   8192               // block window (floats)
#define VALID 7168               // valid outputs per block (halo 1024)
#define C     16                 // elements per lane per array

// tb: 8192 floats (32 KB), multi-purposed:
//   wave-LOCAL transpose scratch (each wave uses only its quarter [wv*1024,+1024)
//   -> NO barriers needed inside the transpose, only one before first phase-B pub)
//   phase-B halo regions (words), consecutive-layer disjoint:
//     R16:[0,1024) R32:[1024,2048) M1:[0,1024) M2:[1024,3072) M4:[3072,7168)
//     M8:[0,8192) with pre-barrier (overlaps M4's read region)
#define R16B 0
#define R32B 1024
#define M1B  0
#define M2B  1024
#define M4B  3072
#define M8B  0

#define KTS  2.885390081777927f  // 2*log2(e): h-state carried pre-scaled by this

// XOR-swizzle for the transpose pattern: word bits 2..4 ^= bits 5..7.
// Touches only bits <10 -> stays inside the wave's 1024-word quarter.
// Measured 0 conflicts in R7/R8/R10.
__device__ __forceinline__ int tswz(int w) { return w ^ (((w >> 5) & 7) << 2); }

__device__ __forceinline__ float fast_tanh_s(float s) {
    // s pre-scaled: s = 2*log2e*y ; tanh(y) = 1 - 2/(2^s+1). Saturates at +/-inf.
    float e = __builtin_amdgcn_exp2f(s);
    float r = __builtin_amdgcn_rcpf(e + 1.0f);
    return fmaf(-2.0f, r, 1.0f);
}

// ---------------- Phase A: contiguous layout, D in {1,2,4,8} ----------------
// h array is K-prescaled (h' = K*h); update is linear so weights unchanged.
// x-path weights arrive pre-multiplied by K so the tanh arg needs no extra mul.
template<int D, int I>
__device__ __forceinline__ void layerA(float (&h)[C], float (&x)[C],
        const float* wh, const float* wx, int lane, int wv,
        float (*hA)[NWV][2][8])
{
    const float wh0 = wh[2*I],       wh1 = wh[2*I+1];
    const float wx0 = KTS*wx[2*I],   wx1 = KTS*wx[2*I+1];
    const int nw = (wv + 1) & (NWV - 1);

    if (lane == 0) {
        #pragma unroll
        for (int j = 0; j < D; ++j) { hA[I][wv][0][j] = h[j]; hA[I][wv][1][j] = x[j]; }
    }
    __syncthreads();

    float th[D], tx[D];
    #pragma unroll
    for (int j = 0; j < D; ++j) {
        th[j] = __shfl(h[j], (lane + 1) & 63, 64);
        tx[j] = __shfl(x[j], (lane + 1) & 63, 64);
        if (lane == 63) { th[j] = hA[I][nw][0][j]; tx[j] = hA[I][nw][1][j]; }
    }
    #pragma unroll
    for (int j = 0; j < C; ++j) {           // ascending j: h[j+D]/x[j+D] still old
        float hd = (j + D < C) ? h[j + D] : th[j + D - C];
        float xd = (j + D < C) ? x[j + D] : tx[j + D - C];
        float hn = fmaf(wh0, h[j], wh1 * hd);
        float s  = fmaf(wx0, x[j], hn);
        s        = fmaf(wx1, xd, s);
        h[j] = hn;
        x[j] = fast_tanh_s(s);
    }
}

// ------------- Phase B: stride-64 interleave, slot k = element lane+64k -------------

// D = R (16 or 32): j+R -> lane (l+R)&63, slot k (+1 for high lanes).
template<int R, int BASE, int I>
__device__ __forceinline__ void layerBR(float (&hh)[C], float (&xx)[C],
        const float* wh, const float* wx, int lane, int wv, float* tb)
{
    const float wh0 = wh[2*I],     wh1 = wh[2*I+1];
    const float wx0 = KTS*wx[2*I], wx1 = KTS*wx[2*I+1];
    const int nw = (wv + 1) & (NWV - 1);

    tb[BASE + (wv*2+0)*64 + lane] = hh[0];     // publish slot 0 (all lanes)
    tb[BASE + (wv*2+1)*64 + lane] = xx[0];
    __syncthreads();

    float fh[C + 1], fx[C + 1];
    #pragma unroll
    for (int k = 0; k < C; ++k) {
        fh[k] = __shfl(hh[k], (lane + R) & 63, 64);
        fx[k] = __shfl(xx[k], (lane + R) & 63, 64);
    }
    fh[C] = 0.0f; fx[C] = 0.0f;
    if (lane >= 64 - R) {                      // slot-16 = next wave's slot 0
        fh[C] = tb[BASE + (nw*2+0)*64 + (lane - (64 - R))];
        fx[C] = tb[BASE + (nw*2+1)*64 + (lane - (64 - R))];
    }
    const bool lo = lane < 64 - R;
    #pragma unroll
    for (int k = 0; k < C; ++k) {
        float hd = lo ? fh[k] : fh[k + 1];
        float xd = lo ? fx[k] : fx[k + 1];
        float hn = fmaf(wh0, hh[k], wh1 * hd);
        float s  = fmaf(wx0, xx[k], hn);
        s        = fmaf(wx1, xd, s);
        hh[k] = hn;
        xx[k] = fast_tanh_s(s);
    }
}

// D = 64*M (M in {1,2,4,8}): pure slot shift; only slots >= 16-M cross the wave.
template<int M, int BASE, bool PREBAR, int I>
__device__ __forceinline__ void layerBM(float (&hh)[C], float (&xx)[C],
        const float* wh, const float* wx, int lane, int wv, float* tb)
{
    const float wh0 = wh[2*I],     wh1 = wh[2*I+1];
    const float wx0 = KTS*wx[2*I], wx1 = KTS*wx[2*I+1];
    const int nw = (wv + 1) & (NWV - 1);

    if constexpr (PREBAR) __syncthreads();     // M=8 overwrites prior read regions

    #pragma unroll
    for (int s = 0; s < M; ++s) {              // publish head slots
        tb[BASE + ((wv*2+0)*M + s)*64 + lane] = hh[s];
        tb[BASE + ((wv*2+1)*M + s)*64 + lane] = xx[s];
    }
    __syncthreads();

    float nh[M], nx[M];
    #pragma unroll
    for (int s = 0; s < M; ++s) {              // next wave's head slots
        nh[s] = tb[BASE + ((nw*2+0)*M + s)*64 + lane];
        nx[s] = tb[BASE + ((nw*2+1)*M + s)*64 + lane];
    }
    #pragma unroll
    for (int k = 0; k < C; ++k) {              // ascending k: hh[k+M] still old
        float hd = (k + M < C) ? hh[k + M] : nh[k + M - C];
        float xd = (k + M < C) ? xx[k + M] : nx[k + M - C];
        float hn = fmaf(wh0, hh[k], wh1 * hd);
        float s  = fmaf(wx0, xx[k], hn);
        s        = fmaf(wx1, xd, s);
        hh[k] = hn;
        xx[k] = fast_tanh_s(s);
    }
}

// launch_bounds arg2: empirical VGPR cap = 256/arg2. arg2=4 -> cap 64;
// natural usage ~40-52 fits (R10 measured 40), runtime residency 4x8=32 waves/CU.
__global__ __launch_bounds__(NT, 4) void rawstack_w8c(
    const float* __restrict__ hin, const float* __restrict__ xin,
    const float* __restrict__ wh,  const float* __restrict__ wx,
    float* __restrict__ out, int T, int Lout)
{
    __shared__ __align__(16) float tb[WIN];    // 32 KB transpose/halo buffer
    __shared__ float hA[4][NWV][2][8];         // 2 KB phase-A head halos

    const int lane = threadIdx.x & 63;
    // wave-uniform -> force into SGPR so all tb/hA addressing is scalar
    const int wv   = __builtin_amdgcn_readfirstlane((int)(threadIdx.x >> 6));
    const int b    = blockIdx.y;
    const int W    = blockIdx.x * VALID;

    const float* hb = hin + (size_t)b * T;
    const float* xb = xin + (size_t)b * T;

    // ---- load contiguous chunks (clamped; garbage stays in invalid tail) ----
    // h is carried pre-scaled by KTS (linear path; output is x, never unscaled h)
    float h[C], x[C];
    #pragma unroll
    for (int q = 0; q < C / 4; ++q) {
        int e = W + wv * 1024 + lane * C + q * 4;
        e = (e > T - 4) ? (T - 4) : e;
        const float4 hv = *(const float4*)(hb + e);
        const float4 xv = *(const float4*)(xb + e);
        h[q*4+0] = KTS*hv.x; h[q*4+1] = KTS*hv.y; h[q*4+2] = KTS*hv.z; h[q*4+3] = KTS*hv.w;
        x[q*4+0] = xv.x;     x[q*4+1] = xv.y;     x[q*4+2] = xv.z;     x[q*4+3] = xv.w;
    }

    // ---- phase A: D = 1,2,4,8 ----
    layerA<1, 0>(h, x, wh, wx, lane, wv, hA);
    layerA<2, 1>(h, x, wh, wx, lane, wv, hA);
    layerA<4, 2>(h, x, wh, wx, lane, wv, hA);
    layerA<8, 3>(h, x, wh, wx, lane, wv, hA);

    // ---- transpose to stride-64 interleave: WAVE-LOCAL (own quarter only),
    //      so no __syncthreads inside; same-wave LDS ordering is hardware-guaranteed.
    float hh[C], xx[C];
    #pragma unroll
    for (int q = 0; q < C / 4; ++q) {
        const int w = tswz(wv * 1024 + lane * C + q * 4);
        *(float4*)&tb[w] = make_float4(h[q*4+0], h[q*4+1], h[q*4+2], h[q*4+3]);
    }
    #pragma unroll
    for (int k = 0; k < C; ++k) hh[k] = tb[tswz(wv * 1024 + lane + 64 * k)];
    #pragma unroll
    for (int q = 0; q < C / 4; ++q) {
        const int w = tswz(wv * 1024 + lane * C + q * 4);
        *(float4*)&tb[w] = make_float4(x[q*4+0], x[q*4+1], x[q*4+2], x[q*4+3]);
    }
    #pragma unroll
    for (int k = 0; k < C; ++k) xx[k] = tb[tswz(wv * 1024 + lane + 64 * k)];
    __syncthreads();   // cross-wave WAR: all transpose reads done before halo pubs

    // ---- phase B: D = 16,32 (shuffle+select), D = 64..512 (slot shift) ----
    layerBR<16, R16B,        4>(hh, xx, wh, wx, lane, wv, tb);
    layerBR<32, R32B,        5>(hh, xx, wh, wx, lane, wv, tb);
    layerBM< 1, M1B,  false, 6>(hh, xx, wh, wx, lane, wv, tb);   // D=64
    layerBM< 2, M2B,  false, 7>(hh, xx, wh, wx, lane, wv, tb);   // D=128
    layerBM< 4, M4B,  false, 8>(hh, xx, wh, wx, lane, wv, tb);   // D=256
    layerBM< 8, M8B,  true,  9>(hh, xx, wh, wx, lane, wv, tb);   // D=512, full tb

    // ---- store (interleaved layout; waves 0..6 hold the 7168 valid outputs) ----
    if (wv < 7) {
        float* ob = out + (size_t)b * Lout;
        const int base = W + wv * 1024 + lane;
        #pragma unroll
        for (int k = 0; k < C; ++k) {
            const int col = base + 64 * k;
            if (col < Lout) ob[col] = xx[k];
        }
    }
}

extern "C" void kernel_launch(void* const* d_in, const int* in_sizes, int n_in,
                              void* d_out, int out_size, void* d_ws, size_t ws_size,
                              hipStream_t stream) {
    const float* h  = (const float*)d_in[0];
    const float* x  = (const float*)d_in[1];
    const float* wh = (const float*)d_in[2];
    const float* wx = (const float*)d_in[3];
    float* out = (float*)d_out;

    const int B    = 64;
    const int T    = in_sizes[0] / B;   // 131072
    const int Lout = out_size / B;      // 130049

    const int blocksPerRow = (Lout + VALID - 1) / VALID;   // 19

    dim3 grid(blocksPerRow, B);
    rawstack_w8c<<<grid, NT, 0, stream>>>(h, x, wh, wx, out, T, Lout);
}